// Round 8
// baseline (85.612 us; speedup 1.0000x reference)
//
#include <hip/hip_runtime.h>

// QuanvolutionHybrid: 8192 x 28x28 fp32 -> 2x2 patches -> 4-qubit circuit
// (Ry encode, 2x [Ry layer + CNOT ring]) -> PauliZ feats [B,784] -> Linear(784,10)
// -> log_softmax. Fully fused, register-resident 16-amplitude simulation.
//
// R8 = R5 structure (best: 83.24us) with W staged in LDS as PACKED BF16 (15.7KB):
//  * LDS/block 31.4KB -> 15.7KB: resident blocks/CU 4 -> 8 (32 waves/CU max),
//    doubling TLP to hide sincos/LDS latency (R5 kernel ~9us vs ~5.1us VALU floor).
//  * W reads ds_read_b128 -> ds_read_b64 (~12 -> ~6 cyc): LDS pipe ~5.6 -> 2.8us.
//  * bf16-W quantization adds ~1e-3 logit error; headroom 0.0156 vs 0.0547 thr.
// R6/R7 lesson: software x-prefetch regressed twice (+1.7us) — plain loop loads.
// Carried: layer-0 Ry folded into encoding sincos (Ry(p0)Ry(a)=Ry(a+p0));
// layer-1 tangent-form Ry with (prod cos)^2 deferred to one fmaf/row;
// 2 rows/wave via 32-lane groups. wire w <-> bit (3-w) of amplitude index.

template <int BIT>
static __device__ __forceinline__ void apply_ry_tan(float (&a)[16], float t) {
#pragma unroll
    for (int i = 0; i < 16; ++i) {
        if (i & (1 << BIT)) continue;
        float a0 = a[i];
        float a1 = a[i | (1 << BIT)];
        a[i]              = fmaf(-t, a1, a0);   // a0 - t*a1
        a[i | (1 << BIT)] = fmaf( t, a0, a1);   // a1 + t*a0
    }
}

template <int CBIT, int TBIT>
static __device__ __forceinline__ void apply_cnot(float (&a)[16]) {
#pragma unroll
    for (int i = 0; i < 16; ++i) {
        if ((i & (1 << CBIT)) && !(i & (1 << TBIT))) {
            float t = a[i];
            a[i] = a[i | (1 << TBIT)];
            a[i | (1 << TBIT)] = t;
        }
    }
}

__global__ __launch_bounds__(256) void quanv_fused_kernel(
    const float* __restrict__ x,       // [B,28,28]
    const float* __restrict__ params,  // [2,4]
    const float* __restrict__ W,       // [10,784]
    const float* __restrict__ bias,    // [10]
    float* __restrict__ out,           // [B,10]
    int B)
{
    __shared__ unsigned int Wp[3920];  // [10][392] u32 = bf16x2 pairs, 15680 B

    {   // cooperative W staging with round-to-nearest-even bf16 packing
        const float2* Wg2 = (const float2*)W;
#pragma unroll
        for (int t = threadIdx.x; t < 3920; t += 256) {
            float2 w = Wg2[t];
            unsigned int a = __float_as_uint(w.x);
            unsigned int b = __float_as_uint(w.y);
            a = (a + 0x7fffu + ((a >> 16) & 1u)) >> 16;          // bf16(w.x) in low16
            b = (b + 0x7fffu + ((b >> 16) & 1u)) & 0xffff0000u;  // bf16(w.y) in high16
            Wp[t] = a | b;
        }
    }
    __syncthreads();   // all threads reach this before any row guard

    const int lane = threadIdx.x & 63;
    const int lid  = lane & 31;                 // lane within 32-lane row group
    const int wave = threadIdx.x >> 6;
    const int row  = blockIdx.x * 8 + wave * 2 + (lane >> 5);
    if (row >= B) return;

    // Layer-0 half-angles (folded into encoding); layer-1 tangents + deferred scale.
    float h0[4], t1w[4];
    float scale2 = 1.0f;
#pragma unroll
    for (int w = 0; w < 4; ++w) {
        h0[w] = 0.5f * params[w];
        float s, c;
        __sincosf(0.5f * params[4 + w], &s, &c);
        t1w[w] = s / c;
        scale2 *= c;
    }
    scale2 *= scale2;   // (prod_w cos)^2, applied once per row after reduction

    float logit[10];
#pragma unroll
    for (int c = 0; c < 10; ++c) logit[c] = 0.0f;

    const float* xrow = x + (size_t)row * 784;

#pragma unroll 1
    for (int p = lid; p < 196; p += 32) {
        const int i = p / 14;
        const int j = p - i * 14;

        // 2x2 patch: wire0=(2i,2j) wire1=(2i,2j+1) wire2=(2i+1,2j) wire3=(2i+1,2j+1)
        const float* b0 = xrow + i * 56 + j * 2;   // 8B-aligned
        float2 r0 = *(const float2*)b0;
        float2 r1 = *(const float2*)(b0 + 28);

        // Encoding Ry(x) fused with layer-0 Ry(p0): half-angle = x/2 + p0/2.
        float c0, s0, c1, s1, c2, s2, c3, s3;
        __sincosf(fmaf(0.5f, r0.x, h0[0]), &s0, &c0);
        __sincosf(fmaf(0.5f, r0.y, h0[1]), &s1, &c1);
        __sincosf(fmaf(0.5f, r1.x, h0[2]), &s2, &c2);
        __sincosf(fmaf(0.5f, r1.y, h0[3]), &s3, &c3);

        // Product state: amp[idx] = p01[idx>>2] * p23[idx&3]  (24 mul)
        float p01[4] = {c0 * c1, c0 * s1, s0 * c1, s0 * s1};
        float p23[4] = {c2 * c3, c2 * s3, s2 * c3, s2 * s3};
        float amp[16];
#pragma unroll
        for (int idx = 0; idx < 16; ++idx)
            amp[idx] = p01[idx >> 2] * p23[idx & 3];

        // Layer-0 CNOT ring (register renames, free).
        apply_cnot<3, 2>(amp);
        apply_cnot<2, 1>(amp);
        apply_cnot<1, 0>(amp);
        apply_cnot<0, 3>(amp);
        // Layer-1 Ry, tangent form (scale deferred): 2 FMA per pair.
        apply_ry_tan<3>(amp, t1w[0]);
        apply_ry_tan<2>(amp, t1w[1]);
        apply_ry_tan<1>(amp, t1w[2]);
        apply_ry_tan<0>(amp, t1w[3]);
        // Layer-1 CNOT ring (renames).
        apply_cnot<3, 2>(amp);
        apply_cnot<2, 1>(amp);
        apply_cnot<1, 0>(amp);
        apply_cnot<0, 3>(amp);

        // PauliZ expvals (unnormalized by scale2) via shared sum tree.
        float pr[16];
#pragma unroll
        for (int idx = 0; idx < 16; ++idx) pr[idx] = amp[idx] * amp[idx];

        float sp[8], dp[8];
#pragma unroll
        for (int k = 0; k < 8; ++k) {
            sp[k] = pr[2 * k] + pr[2 * k + 1];
            dp[k] = pr[2 * k] - pr[2 * k + 1];
        }
        float z3 = ((dp[0] + dp[1]) + (dp[2] + dp[3])) + ((dp[4] + dp[5]) + (dp[6] + dp[7]));
        float t[4], u[4];
#pragma unroll
        for (int k = 0; k < 4; ++k) {
            t[k] = sp[2 * k] + sp[2 * k + 1];
            u[k] = sp[2 * k] - sp[2 * k + 1];
        }
        float z2 = (u[0] + u[1]) + (u[2] + u[3]);
        float z1 = (t[0] - t[1]) + (t[2] - t[3]);
        float z0 = (t[0] + t[1]) - (t[2] + t[3]);

        // Logit accumulation from bf16-packed LDS: one ds_read_b64 per class,
        // lanes stride 8B (2 lanes/bank incl. cross-group broadcast -> free).
        const unsigned int* wp = Wp + 2 * p;
#pragma unroll
        for (int c = 0; c < 10; ++c) {
            uint2 wv = *(const uint2*)(wp + c * 392);
            float w0 = __uint_as_float(wv.x << 16);
            float w1 = __uint_as_float(wv.x & 0xffff0000u);
            float w2 = __uint_as_float(wv.y << 16);
            float w3 = __uint_as_float(wv.y & 0xffff0000u);
            logit[c] = fmaf(z0, w0, fmaf(z1, w1, fmaf(z2, w2, fmaf(z3, w3, logit[c]))));
        }
    }

    // Butterfly reduction within each 32-lane row group (offsets < 32).
#pragma unroll
    for (int o = 16; o > 0; o >>= 1) {
#pragma unroll
        for (int c = 0; c < 10; ++c)
            logit[c] += __shfl_xor(logit[c], o, 64);
    }

    if (lid == 0) {   // lanes 0 and 32 hold their row's full logits
        float v[10];
        float m = -1e30f;
#pragma unroll
        for (int c = 0; c < 10; ++c) {
            v[c] = fmaf(scale2, logit[c], bias[c]);   // deferred tangent-form scale
            m = fmaxf(m, v[c]);
        }
        float sum = 0.f;
#pragma unroll
        for (int c = 0; c < 10; ++c) sum += __expf(v[c] - m);
        float lse = m + __logf(sum);

        float2* o2 = (float2*)(out + (size_t)row * 10);   // 40B rows -> 8B aligned
#pragma unroll
        for (int k = 0; k < 5; ++k)
            o2[k] = make_float2(v[2 * k] - lse, v[2 * k + 1] - lse);
    }
}

extern "C" void kernel_launch(void* const* d_in, const int* in_sizes, int n_in,
                              void* d_out, int out_size, void* d_ws, size_t ws_size,
                              hipStream_t stream) {
    const float* x      = (const float*)d_in[0];
    const float* params = (const float*)d_in[1];
    const float* W      = (const float*)d_in[2];
    const float* bias   = (const float*)d_in[3];
    float* out          = (float*)d_out;

    const int B = in_sizes[0] / 784;          // 8192
    const int blocks = (B + 7) / 8;           // 8 rows per block (2 per wave)

    hipLaunchKernelGGL(quanv_fused_kernel, dim3(blocks), dim3(256), 0, stream,
                       x, params, W, bias, out, B);
}

// Round 9
// 83.500 us; speedup vs baseline: 1.0253x; 1.0253x over previous
//
#include <hip/hip_runtime.h>

// QuanvolutionHybrid: 8192 x 28x28 fp32 -> 2x2 patches -> 4-qubit circuit
// (Ry encode, 2x [Ry layer + CNOT ring]) -> PauliZ feats [B,784] -> Linear(784,10)
// -> log_softmax. Fully fused, register-resident 16-amplitude simulation.
//
// R9 = R5 (best measured: 83.24us) + "#pragma unroll 2" on the patch loop:
// two independent patch chains interleaved in-wave to cover the ~4us latency
// gap (kernel ~9us vs ~5us VALU-issue floor). No occupancy change: grid
// 1024 blocks = 4 blocks/CU (grid-limited), LDS 31.4KB still allows 5.
// Ledger: inner-2-row+halved-grid +1.7us; x-prefetch +1.7us; bf16-W +2.4us —
// all reverted. Carried: layer-0 Ry folded into encoding sincos; layer-1
// tangent-form Ry with (prod cos)^2 deferred; 2 rows/wave via 32-lane groups;
// W fp32 in LDS. wire w <-> bit (3-w) of amplitude index.

template <int BIT>
static __device__ __forceinline__ void apply_ry_tan(float (&a)[16], float t) {
#pragma unroll
    for (int i = 0; i < 16; ++i) {
        if (i & (1 << BIT)) continue;
        float a0 = a[i];
        float a1 = a[i | (1 << BIT)];
        a[i]              = fmaf(-t, a1, a0);   // a0 - t*a1
        a[i | (1 << BIT)] = fmaf( t, a0, a1);   // a1 + t*a0
    }
}

template <int CBIT, int TBIT>
static __device__ __forceinline__ void apply_cnot(float (&a)[16]) {
#pragma unroll
    for (int i = 0; i < 16; ++i) {
        if ((i & (1 << CBIT)) && !(i & (1 << TBIT))) {
            float t = a[i];
            a[i] = a[i | (1 << TBIT)];
            a[i | (1 << TBIT)] = t;
        }
    }
}

__global__ __launch_bounds__(256) void quanv_fused_kernel(
    const float* __restrict__ x,       // [B,28,28]
    const float* __restrict__ params,  // [2,4]
    const float* __restrict__ W,       // [10,784]
    const float* __restrict__ bias,    // [10]
    float* __restrict__ out,           // [B,10]
    int B)
{
    __shared__ float Wl[10 * 784];     // 31360 B; grid-limited 4 blocks/CU

    {   // cooperative W staging: 1960 float4s over 256 threads, coalesced
        const float4* Wg4 = (const float4*)W;
        float4* Wl4 = (float4*)Wl;
#pragma unroll
        for (int t = threadIdx.x; t < 1960; t += 256) Wl4[t] = Wg4[t];
    }
    __syncthreads();   // all threads reach this before any row guard

    const int lane = threadIdx.x & 63;
    const int lid  = lane & 31;                 // lane within 32-lane row group
    const int wave = threadIdx.x >> 6;
    const int row  = blockIdx.x * 8 + wave * 2 + (lane >> 5);
    if (row >= B) return;

    // Layer-0 half-angles (folded into encoding); layer-1 tangents + deferred scale.
    float h0[4], t1w[4];
    float scale2 = 1.0f;
#pragma unroll
    for (int w = 0; w < 4; ++w) {
        h0[w] = 0.5f * params[w];
        float s, c;
        __sincosf(0.5f * params[4 + w], &s, &c);
        t1w[w] = s / c;
        scale2 *= c;
    }
    scale2 *= scale2;   // (prod_w cos)^2, applied once per row after reduction

    float logit[10];
#pragma unroll
    for (int c = 0; c < 10; ++c) logit[c] = 0.0f;

    const float* xrow = x + (size_t)row * 784;

#pragma unroll 2    // interleave two independent patch chains (ILP, no occupancy cost)
    for (int p = lid; p < 196; p += 32) {
        const int i = p / 14;
        const int j = p - i * 14;

        // 2x2 patch: wire0=(2i,2j) wire1=(2i,2j+1) wire2=(2i+1,2j) wire3=(2i+1,2j+1)
        const float* b0 = xrow + i * 56 + j * 2;   // 8B-aligned
        float2 r0 = *(const float2*)b0;
        float2 r1 = *(const float2*)(b0 + 28);

        // Encoding Ry(x) fused with layer-0 Ry(p0): half-angle = x/2 + p0/2.
        float c0, s0, c1, s1, c2, s2, c3, s3;
        __sincosf(fmaf(0.5f, r0.x, h0[0]), &s0, &c0);
        __sincosf(fmaf(0.5f, r0.y, h0[1]), &s1, &c1);
        __sincosf(fmaf(0.5f, r1.x, h0[2]), &s2, &c2);
        __sincosf(fmaf(0.5f, r1.y, h0[3]), &s3, &c3);

        // Product state: amp[idx] = p01[idx>>2] * p23[idx&3]  (24 mul)
        float p01[4] = {c0 * c1, c0 * s1, s0 * c1, s0 * s1};
        float p23[4] = {c2 * c3, c2 * s3, s2 * c3, s2 * s3};
        float amp[16];
#pragma unroll
        for (int idx = 0; idx < 16; ++idx)
            amp[idx] = p01[idx >> 2] * p23[idx & 3];

        // Layer-0 CNOT ring (register renames, free).
        apply_cnot<3, 2>(amp);
        apply_cnot<2, 1>(amp);
        apply_cnot<1, 0>(amp);
        apply_cnot<0, 3>(amp);
        // Layer-1 Ry, tangent form (scale deferred): 2 FMA per pair.
        apply_ry_tan<3>(amp, t1w[0]);
        apply_ry_tan<2>(amp, t1w[1]);
        apply_ry_tan<1>(amp, t1w[2]);
        apply_ry_tan<0>(amp, t1w[3]);
        // Layer-1 CNOT ring (renames).
        apply_cnot<3, 2>(amp);
        apply_cnot<2, 1>(amp);
        apply_cnot<1, 0>(amp);
        apply_cnot<0, 3>(amp);

        // PauliZ expvals (unnormalized by scale2) via shared sum tree.
        float pr[16];
#pragma unroll
        for (int idx = 0; idx < 16; ++idx) pr[idx] = amp[idx] * amp[idx];

        float sp[8], dp[8];
#pragma unroll
        for (int k = 0; k < 8; ++k) {
            sp[k] = pr[2 * k] + pr[2 * k + 1];
            dp[k] = pr[2 * k] - pr[2 * k + 1];
        }
        float z3 = ((dp[0] + dp[1]) + (dp[2] + dp[3])) + ((dp[4] + dp[5]) + (dp[6] + dp[7]));
        float t[4], u[4];
#pragma unroll
        for (int k = 0; k < 4; ++k) {
            t[k] = sp[2 * k] + sp[2 * k + 1];
            u[k] = sp[2 * k] - sp[2 * k + 1];
        }
        float z2 = (u[0] + u[1]) + (u[2] + u[3]);
        float z1 = (t[0] - t[1]) + (t[2] - t[3]);
        float z0 = (t[0] + t[1]) - (t[2] + t[3]);

        // Logit accumulation from LDS: lanes stride 16B (contiguous 512B per group,
        // both 32-lane groups read the SAME addresses -> broadcast, conflict-free).
        const float* wp = Wl + 4 * p;
#pragma unroll
        for (int c = 0; c < 10; ++c) {
            float4 wv = *(const float4*)(wp + c * 784);
            logit[c] = fmaf(z0, wv.x, fmaf(z1, wv.y, fmaf(z2, wv.z, fmaf(z3, wv.w, logit[c]))));
        }
    }

    // Butterfly reduction within each 32-lane row group (offsets < 32).
#pragma unroll
    for (int o = 16; o > 0; o >>= 1) {
#pragma unroll
        for (int c = 0; c < 10; ++c)
            logit[c] += __shfl_xor(logit[c], o, 64);
    }

    if (lid == 0) {   // lanes 0 and 32 hold their row's full logits
        float v[10];
        float m = -1e30f;
#pragma unroll
        for (int c = 0; c < 10; ++c) {
            v[c] = fmaf(scale2, logit[c], bias[c]);   // deferred tangent-form scale
            m = fmaxf(m, v[c]);
        }
        float sum = 0.f;
#pragma unroll
        for (int c = 0; c < 10; ++c) sum += __expf(v[c] - m);
        float lse = m + __logf(sum);

        float2* o2 = (float2*)(out + (size_t)row * 10);   // 40B rows -> 8B aligned
#pragma unroll
        for (int k = 0; k < 5; ++k)
            o2[k] = make_float2(v[2 * k] - lse, v[2 * k + 1] - lse);
    }
}

extern "C" void kernel_launch(void* const* d_in, const int* in_sizes, int n_in,
                              void* d_out, int out_size, void* d_ws, size_t ws_size,
                              hipStream_t stream) {
    const float* x      = (const float*)d_in[0];
    const float* params = (const float*)d_in[1];
    const float* W      = (const float*)d_in[2];
    const float* bias   = (const float*)d_in[3];
    float* out          = (float*)d_out;

    const int B = in_sizes[0] / 784;          // 8192
    const int blocks = (B + 7) / 8;           // 8 rows per block (2 per wave)

    hipLaunchKernelGGL(quanv_fused_kernel, dim3(blocks), dim3(256), 0, stream,
                       x, params, W, bias, out, B);
}